// Round 4
// baseline (277.022 us; speedup 1.0000x reference)
//
#include <hip/hip_runtime.h>

#define BB 64
#define TT 16384
#define EE 512

typedef _Float16 half8 __attribute__((ext_vector_type(8)));
typedef float floatx4 __attribute__((ext_vector_type(4)));

static __device__ __forceinline__ half8 cvt_half8(float4 a, float4 b) {
  half8 h;
  h[0] = (_Float16)a.x; h[1] = (_Float16)a.y; h[2] = (_Float16)a.z; h[3] = (_Float16)a.w;
  h[4] = (_Float16)b.x; h[5] = (_Float16)b.y; h[6] = (_Float16)b.z; h[7] = (_Float16)b.w;
  return h;
}

// global -> LDS direct staging, 16B per lane. LDS dest is wave-uniform base +
// lane*16 (hardware); global src is per-lane (XOR swizzle applied on the
// SOURCE, LDS stays linear -- m173 pattern).
static __device__ __forceinline__ void gload_lds16(const void* g, void* l) {
  __builtin_amdgcn_global_load_lds(
      (const __attribute__((address_space(1))) void*)g,
      (__attribute__((address_space(3))) void*)l, 16, 0, 0);
}

// ---------------------------------------------------------------------------
// Zero the split-K fp32 accumulators. MUST be a kernel (not hipMemsetAsync):
// memset nodes are not reliably captured into the timing graph and d_ws is
// not re-poisoned between replays -> cross-replay accumulation (R1 bug).
// ---------------------------------------------------------------------------
__global__ __launch_bounds__(256) void zero_ws(float4* __restrict__ p) {
  p[blockIdx.x * 256 + threadIdx.x] = (float4){0.f, 0.f, 0.f, 0.f};
}

// ---------------------------------------------------------------------------
// Stage 1 v5: counted-vmcnt pipeline (T3+T4).
// R3 post-mortem: __syncthreads drains vmcnt(0) -> the "prefetch" was fully
// drained at every k-tile barrier; 16 serial L2 round-trips/block reproduced
// the 95us. Fix: 3 LDS buffers, raw s_barrier + s_waitcnt vmcnt(4) (never 0
// in the main loop) -> 2 tiles of loads permanently in flight per wave.
// sched_barrier(0) after each barrier (guide hazard #18). 2x2 wave split
// (wave owns 32x32) cuts LDS reads 10->8/thread and traffic 40->32KB/tile.
// setprio(1) around MFMA cluster (T5). Staging swizzle + XCD map unchanged.
// tiles 0..23: Xq (3m x 8n of 64); 24..87: Xkv (4m x 16n); ntile<8->Wk else Wv
// ---------------------------------------------------------------------------
__global__ __launch_bounds__(256) void proj_gemm(
    const float* __restrict__ x, const float* __restrict__ Wq,
    const float* __restrict__ Wk, const float* __restrict__ Wv,
    float* __restrict__ Xq, float* __restrict__ Xkv)
{
  __shared__ float Abuf[3][64 * 32];   // 8 KB each
  __shared__ float Bbuf[3][64 * 32];   // 8 KB each
  const int t = threadIdx.x;
  const int wave = t >> 6, lane = t & 63;
  const int quad = lane >> 4, l16 = lane & 15;
  const int wr = wave >> 1, wc = wave & 1;     // 2x2 wave grid

  const int orig = blockIdx.x;
  const int logical = (orig & 7) * 352 + (orig >> 3);
  const int chunk = logical / 88;            // 0..31, k-chunk of 512
  const int tile  = logical - chunk * 88;
  const int k0 = chunk << 9;

  int mtile, ntile, cpb, chan_base, ldout;
  const float* Wsrc;
  float* outC;
  if (tile < 24) {
    mtile = tile >> 3; ntile = tile & 7;
    cpb = 3; chan_base = 0; ldout = 512;
    Wsrc = Wq + (size_t)(ntile * 64) * TT;
    outC = Xq;
  } else {
    const int t2 = tile - 24;
    mtile = t2 >> 4; ntile = t2 & 15;
    cpb = 4; chan_base = 3; ldout = 1024;
    Wsrc = (ntile < 8) ? (Wk + (size_t)(ntile * 64) * TT)
                       : (Wv + (size_t)((ntile - 8) * 64) * TT);
    outC = Xkv;
  }

  // staging sources: tile = 512 16B-units, 2 rounds x 256 threads.
  // round r: unit i = (r*4+wave)*64+lane; row = i>>3; u = i&7;
  // source unit = u ^ (row&7)  (swizzle applied source-side)
  const float* aSrc[2];
  const float* bSrc[2];
#pragma unroll
  for (int r = 0; r < 2; ++r) {
    const int i = (r * 4 + wave) * 64 + lane;
    const int row = i >> 3, u = i & 7;
    const int m = mtile * 64 + row;
    const int bidx = (cpb == 3) ? ((m * 21846) >> 16) : (m >> 2);
    const int j = m - bidx * cpb;
    const int swu = (u ^ (row & 7)) << 2;
    aSrc[r] = x + (size_t)(bidx * 7 + chan_base + j) * TT + k0 + swu;
    bSrc[r] = Wsrc + (size_t)row * TT + k0 + swu;
  }

  floatx4 acc[2][2];
#pragma unroll
  for (int rt = 0; rt < 2; ++rt)
#pragma unroll
    for (int ct = 0; ct < 2; ++ct)
      acc[rt][ct] = (floatx4){0.f, 0.f, 0.f, 0.f};

  const int sw = l16 & 7;                      // row&7 for all frag rows below

  auto stage = [&](int kt_, int buf_) {        // 4 gloads / thread / tile
    const int ko = kt_ * 32;
#pragma unroll
    for (int r = 0; r < 2; ++r) {
      gload_lds16(aSrc[r] + ko, &Abuf[buf_][(r * 4 + wave) * 256]);
      gload_lds16(bSrc[r] + ko, &Bbuf[buf_][(r * 4 + wave) * 256]);
    }
  };
  auto compute = [&](int buf_) {
    half8 hb[2], ha[2];
#pragma unroll
    for (int ct = 0; ct < 2; ++ct) {
      const int brow = wc * 32 + ct * 16 + l16;
      float4 b0 = *(const float4*)&Bbuf[buf_][brow * 32 + ((((quad << 1) | 0) ^ sw) << 2)];
      float4 b1 = *(const float4*)&Bbuf[buf_][brow * 32 + ((((quad << 1) | 1) ^ sw) << 2)];
      hb[ct] = cvt_half8(b0, b1);
    }
#pragma unroll
    for (int rt = 0; rt < 2; ++rt) {
      const int arow = wr * 32 + rt * 16 + l16;
      float4 a0 = *(const float4*)&Abuf[buf_][arow * 32 + ((((quad << 1) | 0) ^ sw) << 2)];
      float4 a1 = *(const float4*)&Abuf[buf_][arow * 32 + ((((quad << 1) | 1) ^ sw) << 2)];
      ha[rt] = cvt_half8(a0, a1);
    }
    __builtin_amdgcn_s_setprio(1);
#pragma unroll
    for (int rt = 0; rt < 2; ++rt)
#pragma unroll
      for (int ct = 0; ct < 2; ++ct)
        acc[rt][ct] = __builtin_amdgcn_mfma_f32_16x16x32_f16(ha[rt], hb[ct], acc[rt][ct], 0, 0, 0);
    __builtin_amdgcn_s_setprio(0);
  };

  // prologue: 2 tiles in flight, wait only the oldest (tile 0)
  stage(0, 0);
  stage(1, 1);
  asm volatile("s_waitcnt vmcnt(4)" ::: "memory");
  __builtin_amdgcn_s_barrier();
  __builtin_amdgcn_sched_barrier(0);

  int cur = 0;
#pragma unroll
  for (int kt = 0; kt < 14; ++kt) {
    const int nx2 = (cur + 2 >= 3) ? cur - 1 : cur + 2;   // (kt+2)%3
    stage(kt + 2, nx2);
    compute(cur);
    asm volatile("s_waitcnt vmcnt(4)" ::: "memory");      // tile kt+1 ready; kt+2 in flight
    __builtin_amdgcn_s_barrier();
    __builtin_amdgcn_sched_barrier(0);
    cur = (cur + 1 >= 3) ? 0 : cur + 1;
  }
  compute(cur);                                           // kt=14, buf 2
  asm volatile("s_waitcnt vmcnt(0)" ::: "memory");        // tail drain
  __builtin_amdgcn_s_barrier();
  __builtin_amdgcn_sched_barrier(0);
  compute((cur + 1 >= 3) ? 0 : cur + 1);                  // kt=15, buf 0

  // epilogue: C/D layout col=lane&15, row=quad*4+reg
#pragma unroll
  for (int rt = 0; rt < 2; ++rt) {
#pragma unroll
    for (int ct = 0; ct < 2; ++ct) {
      const int gr = mtile * 64 + wr * 32 + rt * 16 + quad * 4;
      const int gc = ntile * 64 + wc * 32 + ct * 16 + l16;
#pragma unroll
      for (int rg = 0; rg < 4; ++rg)
        atomicAdd(&outC[(size_t)(gr + rg) * ldout + gc], acc[rt][ct][rg]);
    }
  }
}

// ---------------------------------------------------------------------------
// Stage 2: per (batch, 64-wide e-chunk): build K(16x512), VW(3x512), Q(16x64)
// in LDS, then per e-row: S = 0.25*Q^T K, softmax over f, u[o,e]=P·VW[o]/den.
// (unchanged -- verified correct)
// ---------------------------------------------------------------------------
__global__ __launch_bounds__(256) void attn_mid(
    const float* __restrict__ Xq, const float* __restrict__ Xkv,
    const float* __restrict__ W1, const float* __restrict__ W2,
    const float* __restrict__ W3,
    const float* __restrict__ bq, const float* __restrict__ bk,
    const float* __restrict__ bv, _Float16* __restrict__ U)
{
  __shared__ float Ks[16][512];
  __shared__ float VW[3][512];
  __shared__ float Qs[16][64];
  __shared__ float Xs[4][512];
  __shared__ float W1s[48], W2s[64], W3s[48], W32s[12], w3sum[3];
  const int t = threadIdx.x;
  const int b = blockIdx.y;
  const int e0 = blockIdx.x * 64;

  if (t < 48) W1s[t] = W1[t];
  if (t >= 64 && t < 128) W2s[t - 64] = W2[t - 64];
  if (t >= 128 && t < 176) W3s[t - 128] = W3[t - 128];
  __syncthreads();
  if (t < 12) {                       // W32[o][j] = sum_c W3[o][c]*W2[c][j]
    const int o = t >> 2, jj = t & 3;
    float s = 0.f;
    for (int c = 0; c < 16; ++c) s += W3s[o * 16 + c] * W2s[c * 4 + jj];
    W32s[t] = s;
  }
  if (t >= 16 && t < 19) {
    const int o = t - 16;
    float s = 0.f;
    for (int c = 0; c < 16; ++c) s += W3s[o * 16 + c];
    w3sum[o] = s;
  }
  // stage Xk, build K
  for (int i = t; i < 2048; i += 256) {
    const int jj = i >> 9, f = i & 511;
    Xs[jj][f] = Xkv[(size_t)(b * 4 + jj) * 1024 + f];
  }
  __syncthreads();
  for (int i = t; i < 8192; i += 256) {
    const int c = i >> 9, f = i & 511;
    float s = bk[f];
#pragma unroll
    for (int jj = 0; jj < 4; ++jj) s += W2s[c * 4 + jj] * Xs[jj][f];
    Ks[c][f] = s;
  }
  __syncthreads();
  // stage Xv, build VW
  for (int i = t; i < 2048; i += 256) {
    const int jj = i >> 9, f = i & 511;
    Xs[jj][f] = Xkv[(size_t)(b * 4 + jj) * 1024 + 512 + f];
  }
  __syncthreads();
  for (int i = t; i < 1536; i += 256) {
    const int o = i >> 9, f = i & 511;
    float s = w3sum[o] * bv[f];
#pragma unroll
    for (int jj = 0; jj < 4; ++jj) s += W32s[o * 4 + jj] * Xs[jj][f];
    VW[o][f] = s;
  }
  // build Q for this e-chunk
  for (int i = t; i < 1024; i += 256) {
    const int c = i >> 6, el = i & 63;
    float s = bq[e0 + el];
#pragma unroll
    for (int jj = 0; jj < 3; ++jj)
      s += W1s[c * 3 + jj] * Xq[(size_t)(b * 3 + jj) * 512 + e0 + el];
    Qs[c][el] = s;
  }
  __syncthreads();

  const int wave = t >> 6, lane = t & 63;
  float vwr[3][8];
#pragma unroll
  for (int o = 0; o < 3; ++o) {
    float4 va = *(const float4*)&VW[o][lane * 8];
    float4 vb = *(const float4*)&VW[o][lane * 8 + 4];
    vwr[o][0] = va.x; vwr[o][1] = va.y; vwr[o][2] = va.z; vwr[o][3] = va.w;
    vwr[o][4] = vb.x; vwr[o][5] = vb.y; vwr[o][6] = vb.z; vwr[o][7] = vb.w;
  }

  for (int g = 0; g < 4; ++g) {       // 4 groups of 4 e-rows per wave
    const int el0 = wave * 16 + g * 4;
    float s[4][8];
#pragma unroll
    for (int e = 0; e < 4; ++e)
#pragma unroll
      for (int i = 0; i < 8; ++i) s[e][i] = 0.f;
#pragma unroll
    for (int c = 0; c < 16; ++c) {
      float4 k0 = *(const float4*)&Ks[c][lane * 8];
      float4 k1 = *(const float4*)&Ks[c][lane * 8 + 4];
      float4 qv = *(const float4*)&Qs[c][el0];
      float qa[4] = {qv.x, qv.y, qv.z, qv.w};
#pragma unroll
      for (int e = 0; e < 4; ++e) {
        const float q = qa[e];
        s[e][0] += q * k0.x; s[e][1] += q * k0.y; s[e][2] += q * k0.z; s[e][3] += q * k0.w;
        s[e][4] += q * k1.x; s[e][5] += q * k1.y; s[e][6] += q * k1.z; s[e][7] += q * k1.w;
      }
    }
#pragma unroll
    for (int e = 0; e < 4; ++e) {
      float mx = s[e][0];
#pragma unroll
      for (int i = 1; i < 8; ++i) mx = fmaxf(mx, s[e][i]);
#pragma unroll
      for (int off = 32; off; off >>= 1) mx = fmaxf(mx, __shfl_xor(mx, off));
      float p[8], sum = 0.f;
#pragma unroll
      for (int i = 0; i < 8; ++i) { p[i] = __expf(0.25f * (s[e][i] - mx)); sum += p[i]; }
      float u0 = 0.f, u1 = 0.f, u2 = 0.f;
#pragma unroll
      for (int i = 0; i < 8; ++i) {
        u0 += p[i] * vwr[0][i];
        u1 += p[i] * vwr[1][i];
        u2 += p[i] * vwr[2][i];
      }
#pragma unroll
      for (int off = 32; off; off >>= 1) {
        sum += __shfl_xor(sum, off);
        u0  += __shfl_xor(u0, off);
        u1  += __shfl_xor(u1, off);
        u2  += __shfl_xor(u2, off);
      }
      if (lane == 0) {
        const float inv = 1.0f / sum;
        const size_t base = (size_t)b * 3 * 512 + (e0 + el0 + e);
        U[base]        = (_Float16)(u0 * inv);
        U[base + 512]  = (_Float16)(u1 * inv);
        U[base + 1024] = (_Float16)(u2 * inv);
      }
    }
  }
}

// ---------------------------------------------------------------------------
// Stage 3 v5: counted-vmcnt pipeline (same surgery as proj_gemm).
// out[r][t] = sum_e U[r][e]*Wo[t][e] + x[(b*7+o)][t] + w3sum[o]*bo[t]
// M=192, N=16384, K=512. 3 gloads/thread/tile (A 1, B 2) -> steady-state
// vmcnt(3). LDS 3x(4+8)=36KB -> 4 blocks/CU.
// ---------------------------------------------------------------------------
__global__ __launch_bounds__(256) void out_gemm(
    const _Float16* __restrict__ U, const float* __restrict__ Wo,
    const float* __restrict__ x, const float* __restrict__ bo,
    const float* __restrict__ W3, float* __restrict__ outY)
{
  __shared__ _Float16 Au[3][64 * 32];  // 4 KB each
  __shared__ float    Bw[3][64 * 32];  // 8 KB each
  const int t = threadIdx.x;
  const int wave = t >> 6, lane = t & 63;
  const int quad = lane >> 4, l16 = lane & 15;
  const int mtile = blockIdx.y, ntile = blockIdx.x;

  float w3s[3];
#pragma unroll
  for (int o = 0; o < 3; ++o) {
    float s = 0.f;
#pragma unroll
    for (int c = 0; c < 16; ++c) s += W3[o * 16 + c];
    w3s[o] = s;
  }

  // A staging: 256 units of 16B (8 halfs); unit i = wave*64+lane;
  // row = i>>2, u = i&3; src unit = u ^ (row&3)
  const int ai = wave * 64 + lane;
  const int arow_s = ai >> 2, au = ai & 3;
  const _Float16* aSrc = U + (size_t)(mtile * 64 + arow_s) * EE
                           + ((au ^ (arow_s & 3)) << 3);
  // B staging: 512 units, 2 rounds; row = i>>3, u = i&7; src unit = u^(row&7)
  const float* bSrc[2];
#pragma unroll
  for (int r = 0; r < 2; ++r) {
    const int i = (r * 4 + wave) * 64 + lane;
    const int row = i >> 3, u = i & 7;
    bSrc[r] = Wo + (size_t)(ntile * 64 + row) * EE + ((u ^ (row & 7)) << 2);
  }

  floatx4 acc[4];
#pragma unroll
  for (int rt = 0; rt < 4; ++rt) acc[rt] = (floatx4){0.f, 0.f, 0.f, 0.f};

  const int brow = wave * 16 + l16;
  const int bsw = brow & 7;

  auto stage = [&](int kt_, int buf_) {        // 3 gloads / thread / tile
    gload_lds16(aSrc + kt_ * 32, &Au[buf_][wave * 512]);
#pragma unroll
    for (int r = 0; r < 2; ++r)
      gload_lds16(bSrc[r] + kt_ * 32, &Bw[buf_][(r * 4 + wave) * 256]);
  };
  auto compute = [&](int buf_) {
    float4 b0 = *(const float4*)&Bw[buf_][brow * 32 + ((((quad << 1) | 0) ^ bsw) << 2)];
    float4 b1 = *(const float4*)&Bw[buf_][brow * 32 + ((((quad << 1) | 1) ^ bsw) << 2)];
    const half8 hb = cvt_half8(b0, b1);
    half8 ha[4];
#pragma unroll
    for (int rt = 0; rt < 4; ++rt) {
      const int arow = rt * 16 + l16;
      ha[rt] = *(const half8*)&Au[buf_][arow * 32 + ((quad ^ (arow & 3)) << 3)];
    }
    __builtin_amdgcn_s_setprio(1);
#pragma unroll
    for (int rt = 0; rt < 4; ++rt)
      acc[rt] = __builtin_amdgcn_mfma_f32_16x16x32_f16(ha[rt], hb, acc[rt], 0, 0, 0);
    __builtin_amdgcn_s_setprio(0);
  };

  stage(0, 0);
  stage(1, 1);
  asm volatile("s_waitcnt vmcnt(3)" ::: "memory");
  __builtin_amdgcn_s_barrier();
  __builtin_amdgcn_sched_barrier(0);

  int cur = 0;
#pragma unroll
  for (int kt = 0; kt < 14; ++kt) {
    const int nx2 = (cur + 2 >= 3) ? cur - 1 : cur + 2;
    stage(kt + 2, nx2);
    compute(cur);
    asm volatile("s_waitcnt vmcnt(3)" ::: "memory");
    __builtin_amdgcn_s_barrier();
    __builtin_amdgcn_sched_barrier(0);
    cur = (cur + 1 >= 3) ? 0 : cur + 1;
  }
  compute(cur);
  asm volatile("s_waitcnt vmcnt(0)" ::: "memory");
  __builtin_amdgcn_s_barrier();
  __builtin_amdgcn_sched_barrier(0);
  compute((cur + 1 >= 3) ? 0 : cur + 1);

  const int tc = ntile * 64 + wave * 16 + l16;
  const float bot = bo[tc];
#pragma unroll
  for (int rt = 0; rt < 4; ++rt) {
    const int gr = mtile * 64 + rt * 16 + quad * 4;
#pragma unroll
    for (int rg = 0; rg < 4; ++rg) {
      const int rr = gr + rg;
      const int bb = rr / 3, oo = rr - bb * 3;
      const float v = acc[rt][rg]
                    + x[(size_t)(bb * 7 + oo) * TT + tc]
                    + w3s[oo] * bot;
      outY[(size_t)rr * TT + tc] = v;
    }
  }
}

extern "C" void kernel_launch(void* const* d_in, const int* in_sizes, int n_in,
                              void* d_out, int out_size, void* d_ws, size_t ws_size,
                              hipStream_t stream) {
  const float* x  = (const float*)d_in[0];
  const float* W1 = (const float*)d_in[1];
  const float* W2 = (const float*)d_in[2];
  const float* Wq = (const float*)d_in[3];
  const float* bq = (const float*)d_in[4];
  const float* Wk = (const float*)d_in[5];
  const float* bk = (const float*)d_in[6];
  const float* Wv = (const float*)d_in[7];
  const float* bv = (const float*)d_in[8];
  const float* Wo = (const float*)d_in[9];
  const float* bo = (const float*)d_in[10];
  const float* W3 = (const float*)d_in[11];
  float* out = (float*)d_out;

  char* ws = (char*)d_ws;
  float* Xq      = (float*)ws;                  // 192*512  fp32 = 393216 B
  float* Xkv     = (float*)(ws + 393216);       // 256*1024 fp32 = 1048576 B
  _Float16* U    = (_Float16*)(ws + 1441792);   // 192*512  fp16 = 196608 B

  // zero the split-K accumulators (kernel, NOT hipMemsetAsync)
  zero_ws<<<dim3(352), 256, 0, stream>>>((float4*)ws);

  // merged projections: 88 MN-tiles x 32 k-chunks = 2816 blocks
  proj_gemm<<<dim3(2816), 256, 0, stream>>>(x, Wq, Wk, Wv, Xq, Xkv);
  // attention middle -> U (192 x 512 fp16)
  attn_mid<<<dim3(8, BB), 256, 0, stream>>>(Xq, Xkv, W1, W2, W3, bq, bk, bv, U);
  // final projection + residual + bias
  out_gemm<<<dim3(256, 3), 256, 0, stream>>>(U, Wo, x, bo, W3, out);
}